// Round 13
// baseline (207.137 us; speedup 1.0000x reference)
//
#include <hip/hip_runtime.h>

typedef __attribute__((ext_vector_type(8))) short short8;
typedef __attribute__((ext_vector_type(4))) float f32x4;

#define DEVI __device__ __forceinline__

DEVI unsigned fbits(float f) { return __builtin_bit_cast(unsigned, f); }
DEVI float bf2f(unsigned u) {   // low 16 bits -> f32
    unsigned v = u << 16;
    return __builtin_bit_cast(float, v);
}
DEVI unsigned short f2bf(float f) {
    unsigned u = __builtin_bit_cast(unsigned, f);
    u += 0x7fffu + ((u >> 16) & 1u);   // RNE
    return (unsigned short)(u >> 16);
}
// pack hi16(a)|hi16(b)<<16 (bf16 truncation, 1 instr)
DEVI unsigned pktrunc(float a, float b) {
    return __builtin_amdgcn_perm(fbits(b), fbits(a), 0x07060302u);
}
// async global->LDS, 16 B per lane; LDS dest = uniform base + lane*16
DEVI void async16(const unsigned short* g, unsigned short* l) {
    __builtin_amdgcn_global_load_lds(
        (const __attribute__((address_space(1))) void*)g,
        (__attribute__((address_space(3))) void*)l,
        16, 0, 0);
}
#define BAR()    asm volatile("s_barrier" ::: "memory")
#define BARF()   asm volatile("s_waitcnt lgkmcnt(0)\ns_barrier" ::: "memory")
#define WAITV0() asm volatile("s_waitcnt vmcnt(0)" ::: "memory")

#define SCL 0.18033688011112042f   // log2(e) / sqrt(64), folded into Q

// ---------------------------------------------------------------- prep
// blocks [0,6144): x f32 -> xb bf16 (float4 path)
// blocks [6144,7872): w[768][2304] f32 -> wt[2304][768] bf16 (tiled transpose)
__global__ __launch_bounds__(256) void kprep(const float* __restrict__ x,
                                             unsigned short* __restrict__ xb,
                                             const float* __restrict__ w,
                                             unsigned short* __restrict__ wt) {
    const int bid = blockIdx.x, tid = threadIdx.x;
    if (bid < 6144) {
        const int i = (bid * 256 + tid) * 4;
        const float4 v = *(const float4*)&x[i];
        uint2 pk;
        pk.x = (unsigned)f2bf(v.x) | ((unsigned)f2bf(v.y) << 16);
        pk.y = (unsigned)f2bf(v.z) | ((unsigned)f2bf(v.w) << 16);
        *(uint2*)&xb[i] = pk;
    } else {
        __shared__ float t[32][33];
        const int b2 = bid - 6144;
        const int n0 = (b2 % 72) * 32, k0 = (b2 / 72) * 32;
        const int tx = tid & 31, ty = tid >> 5;   // 32 x 8
#pragma unroll
        for (int i = 0; i < 4; i++)
            t[ty + i * 8][tx] = w[(k0 + ty + i * 8) * 2304 + n0 + tx];
        __syncthreads();
#pragma unroll
        for (int i = 0; i < 4; i++)
            wt[(n0 + ty + i * 8) * 768 + k0 + tx] = f2bf(t[tx][ty + i * 8]);
    }
}

// ---------------------------------------------------------------- QKV GEMM
// A = xb [8192][768] bf16, Bt = wt [2304][768] bf16; C = A*Bt^T + bias.
// Fragment-order LDS, async16 staging, 2-buffer depth-1 pipeline in a
// 34.8 KB pool (4 blocks/CU).  Epilogue: q/k direct scatter (q scaled by
// SCL); v via LDS transpose -> coalesced short8 stores (Vt layout).
__global__ __launch_bounds__(256) void kgemm(
        const unsigned short* __restrict__ xb,
        const unsigned short* __restrict__ wt,
        const float* __restrict__ bias,
        unsigned short* __restrict__ q,
        unsigned short* __restrict__ k_,
        unsigned short* __restrict__ vt) {
    // staging: As[b] @ b*4096, Bs[b] @ 8192 + b*4096 (b in 0..1)
    // epilogue v-tile [n=128][stride 136] = 17408 elems (34.8 KB)
    __shared__ __align__(16) unsigned short pool[17408];
    const int tid = threadIdx.x;
    const int w = tid >> 6, lane = tid & 63;
    const int wm = w >> 1, wn = w & 1;
    const int m0 = blockIdx.y * 128, n0 = blockIdx.x * 128;
    const int gr = lane & 15, gc = (lane >> 4) * 8;

    f32x4 acc[4][4] = {};

    auto issue = [&](int kk, int b) {
#pragma unroll
        for (int j = 0; j < 2; j++) {
            const int t = w + j * 4;
            async16(&xb[(m0 + t * 16 + gr) * 768 + kk + gc],
                    &pool[b * 4096 + t * 512 + lane * 8]);
            async16(&wt[(n0 + t * 16 + gr) * 768 + kk + gc],
                    &pool[8192 + b * 4096 + t * 512 + lane * 8]);
        }
    };

    issue(0, 0);

    for (int it = 0; it < 24; it++) {
        const int cur = it & 1;
        WAITV0();          // this wave's DMAs for tile `it` complete
        BAR();             // all waves' tiles resident; prev reads done
        if (it + 1 < 24) issue((it + 1) * 32, cur ^ 1);

        short8 af[4], bf[4];
#pragma unroll
        for (int mi = 0; mi < 4; mi++)
            af[mi] = *(const short8*)&pool[cur * 4096 + (wm * 4 + mi) * 512 + lane * 8];
#pragma unroll
        for (int ni = 0; ni < 4; ni++)
            bf[ni] = *(const short8*)&pool[8192 + cur * 4096 + (wn * 4 + ni) * 512 + lane * 8];
#pragma unroll
        for (int mi = 0; mi < 4; mi++)
#pragma unroll
            for (int ni = 0; ni < 4; ni++)
                acc[mi][ni] = __builtin_amdgcn_mfma_f32_16x16x32_bf16(
                    af[mi], bf[ni], acc[mi][ni], 0, 0, 0);
    }

    const int which = n0 / 768;        // block-uniform: 0=q 1=k 2=v
    const int bb = m0 >> 10, sbase = m0 & 1023;

    if (which == 2) {
        BAR();                         // all staging reads complete
        // C-tile -> LDS transposed [n][136] (bias fused), packed m-quads
#pragma unroll
        for (int mi = 0; mi < 4; mi++) {
            const int mloc = wm * 64 + mi * 16 + (lane >> 4) * 4;
#pragma unroll
            for (int ni = 0; ni < 4; ni++) {
                const int nl = wn * 64 + ni * 16 + gr;
                const float bv = bias[n0 + nl];
                uint2 pk;
                pk.x = pktrunc(acc[mi][ni][0] + bv, acc[mi][ni][1] + bv);
                pk.y = pktrunc(acc[mi][ni][2] + bv, acc[mi][ni][3] + bv);
                *(uint2*)&pool[nl * 136 + mloc] = pk;
            }
        }
        BARF();
        const int h0 = (n0 - 1536) >> 6;
#pragma unroll
        for (int cc = 0; cc < 8; cc++) {
            const int nl = cc * 16 + (tid >> 4);
            const int mc = (tid & 15) * 8;
            short8 vv = *(const short8*)&pool[nl * 136 + mc];
            const int h = h0 + (nl >> 6), d = nl & 63;
            *(short8*)&vt[((bb * 12 + h) * 64 + d) * 1024 + sbase + mc] = vv;
        }
    } else {
        const float qscl = (which == 0) ? SCL : 1.0f;
        const int col0 = n0 + wn * 64;
#pragma unroll
        for (int mi = 0; mi < 4; mi++) {
#pragma unroll
            for (int ni = 0; ni < 4; ni++) {
                const int n_ = col0 + ni * 16 + gr;
                const float bv = bias[n_];
                const int r7 = n_ % 768;
                const int h = r7 >> 6, d = r7 & 63;
                const int bh = bb * 12 + h;
#pragma unroll
                for (int r = 0; r < 4; r++) {
                    const int s = sbase + wm * 64 + mi * 16 + (lane >> 4) * 4 + r;
                    const unsigned short o = f2bf((acc[mi][ni][r] + bv) * qscl);
                    if (which == 0) q[(bh * 1024 + s) * 64 + d] = o;
                    else            k_[(bh * 1024 + s) * 64 + d] = o;
                }
            }
        }
    }
}

// ---------------------------------------------------------------- attention
// S^T = K*Q^T (Q pre-scaled by SCL), softmax over keys WITHOUT online max.
// O^T = V^T*P^T.  Fragment-order async staging, 2-buffer depth-1 pipeline.
// Ps halved (ks-split relayout) -> 40 KB LDS -> 4 blocks/CU.
__global__ __launch_bounds__(256) void kattn(
        const unsigned short* __restrict__ q,
        const unsigned short* __restrict__ k_,
        const unsigned short* __restrict__ vt,
        unsigned short* __restrict__ attnb) {
    __shared__ __align__(16) unsigned short Ks[2][8 * 512];
    __shared__ __align__(16) unsigned short Vs[2][8 * 512];
    __shared__ __align__(16) unsigned short Ps[4][2 * 512];
    const int tid = threadIdx.x;
    const int w = tid >> 6, lane = tid & 63;
    const int qt = blockIdx.x;          // 8
    const int bh = blockIdx.y;          // 96
    const int bb = bh / 12, h = bh % 12;
    const unsigned short* qb = q + bh * 1024 * 64;
    const unsigned short* kb = k_ + bh * 1024 * 64;
    const unsigned short* vb = vt + bh * 64 * 1024;

    const int frow = lane & 15;         // q-row within 16-tile
    const int grp = lane >> 4;
    const int m0 = qt * 128 + w * 32;

    auto issue = [&](int t0, int b) {
#pragma unroll
        for (int j = 0; j < 2; j++) {
            const int t = w * 2 + j, ti = t >> 1, ks = t & 1;
            async16(&kb[(t0 + ti * 16 + frow) * 64 + ks * 32 + grp * 8], &Ks[b][t * 512]);
            async16(&vb[(ti * 16 + frow) * 1024 + t0 + ks * 32 + grp * 8], &Vs[b][t * 512]);
        }
    };

    short8 qf[2][2];
#pragma unroll
    for (int mi = 0; mi < 2; mi++)
#pragma unroll
        for (int ks = 0; ks < 2; ks++)
            qf[mi][ks] = *(const short8*)&qb[(m0 + mi * 16 + frow) * 64 + ks * 32 + grp * 8];

    issue(0, 0);

    f32x4 oacc[2][4] = {};
    float rsum[2] = {0.f, 0.f};         // per-lane partial (16 keys/iter)

    for (int tt = 0; tt < 16; tt++) {
        const int cur = tt & 1;
        WAITV0();
        BAR();
        if (tt + 1 < 16) issue((tt + 1) * 64, cur ^ 1);

        // S^T = K * Q^T
        f32x4 sacc[4][2] = {};
#pragma unroll
        for (int ks = 0; ks < 2; ks++) {
            short8 kf[4];
#pragma unroll
            for (int ni = 0; ni < 4; ni++)
                kf[ni] = *(const short8*)&Ks[cur][(ni * 2 + ks) * 512 + lane * 8];
#pragma unroll
            for (int ni = 0; ni < 4; ni++)
#pragma unroll
                for (int mi = 0; mi < 2; mi++)
                    sacc[ni][mi] = __builtin_amdgcn_mfma_f32_16x16x32_bf16(
                        kf[ni], qf[mi][ks], sacc[ni][mi], 0, 0, 0);
        }

        // softmax numerators: p = exp2(s) (scale pre-folded into Q)
#pragma unroll
        for (int mi = 0; mi < 2; mi++) {
            float ps = 0.f;
#pragma unroll
            for (int ni = 0; ni < 4; ni++)
#pragma unroll
                for (int r = 0; r < 4; r++) {
                    const float p = exp2f(sacc[ni][mi][r]);
                    sacc[ni][mi][r] = p;
                    ps += p;
                }
            rsum[mi] += ps;
        }

        // PV per ks-half: relayout that half's P^T, then MFMA
#pragma unroll
        for (int ks = 0; ks < 2; ks++) {
            short8 vf[4], pf[2];
#pragma unroll
            for (int mi = 0; mi < 2; mi++)
#pragma unroll
                for (int nj = 0; nj < 2; nj++) {
                    const int ni = ks * 2 + nj;
                    uint2 pk;
                    pk.x = pktrunc(sacc[ni][mi][0], sacc[ni][mi][1]);
                    pk.y = pktrunc(sacc[ni][mi][2], sacc[ni][mi][3]);
                    const int dlane = frow + (((ni << 1) + (grp >> 1)) & 3) * 16;
                    *(uint2*)&Ps[w][mi * 512 + dlane * 8 + (grp & 1) * 4] = pk;
                }
#pragma unroll
            for (int di = 0; di < 4; di++)
                vf[di] = *(const short8*)&Vs[cur][(di * 2 + ks) * 512 + lane * 8];
#pragma unroll
            for (int mi = 0; mi < 2; mi++)
                pf[mi] = *(const short8*)&Ps[w][mi * 512 + lane * 8];
#pragma unroll
            for (int mi = 0; mi < 2; mi++)
#pragma unroll
                for (int di = 0; di < 4; di++)
                    oacc[mi][di] = __builtin_amdgcn_mfma_f32_16x16x32_bf16(
                        vf[di], pf[mi], oacc[mi][di], 0, 0, 0);
        }
    }

    // epilogue: reduce rsum across the 4 grp lanes, O^T/l -> attnb (bf16)
#pragma unroll
    for (int mi = 0; mi < 2; mi++) {
        float s2 = rsum[mi];
        s2 += __shfl_xor(s2, 16, 64);
        s2 += __shfl_xor(s2, 32, 64);
        const float inv = 1.0f / s2;
        const int s = m0 + mi * 16 + frow;
#pragma unroll
        for (int di = 0; di < 4; di++) {
            f32x4 o = oacc[mi][di] * inv;
            const int d0 = di * 16 + grp * 4;
            uint2 pk;
            pk.x = (unsigned)f2bf(o[0]) | ((unsigned)f2bf(o[1]) << 16);
            pk.y = (unsigned)f2bf(o[2]) | ((unsigned)f2bf(o[3]) << 16);
            *(uint2*)&attnb[(bb * 1024 + s) * 768 + h * 64 + d0] = pk;
        }
    }
}

// ---------------------------------------------------------------- residual + LN
// y = LN(x + attn); x f32 (float4 loads), attn bf16 (uint2 loads), out f32.
__global__ __launch_bounds__(192) void kln(
        const float* __restrict__ x,
        const unsigned short* __restrict__ attnb,
        const float* __restrict__ gamma,
        const float* __restrict__ beta,
        float* __restrict__ out) {
    __shared__ float red[6];
    const int row = blockIdx.x;
    const int tid = threadIdx.x;
    const int e = tid * 4;
    const float4 xv = *(const float4*)&x[row * 768 + e];
    const uint2 av = *(const uint2*)&attnb[row * 768 + e];
    float y0 = xv.x + bf2f(av.x & 0xffffu);
    float y1 = xv.y + bf2f(av.x >> 16);
    float y2 = xv.z + bf2f(av.y & 0xffffu);
    float y3 = xv.w + bf2f(av.y >> 16);
    float sum = y0 + y1 + y2 + y3;
    float sumsq = y0 * y0 + y1 * y1 + y2 * y2 + y3 * y3;
#pragma unroll
    for (int o = 1; o < 64; o <<= 1) {
        sum += __shfl_xor(sum, o, 64);
        sumsq += __shfl_xor(sumsq, o, 64);
    }
    const int w = tid >> 6, lane = tid & 63;
    if (lane == 0) { red[w] = sum; red[3 + w] = sumsq; }
    __syncthreads();
    sum = red[0] + red[1] + red[2];
    sumsq = red[3] + red[4] + red[5];
    const float mean = sum * (1.0f / 768.0f);
    const float var = sumsq * (1.0f / 768.0f) - mean * mean;
    const float rs = rsqrtf(var + 1e-5f);
    const float4 gv = *(const float4*)&gamma[e];
    const float4 bv = *(const float4*)&beta[e];
    float4 ov;
    ov.x = (y0 - mean) * rs * gv.x + bv.x;
    ov.y = (y1 - mean) * rs * gv.y + bv.y;
    ov.z = (y2 - mean) * rs * gv.z + bv.z;
    ov.w = (y3 - mean) * rs * gv.w + bv.w;
    *(float4*)&out[row * 768 + e] = ov;
}

// ---------------------------------------------------------------- launch
extern "C" void kernel_launch(void* const* d_in, const int* in_sizes, int n_in,
                              void* d_out, int out_size, void* d_ws, size_t ws_size,
                              hipStream_t stream) {
    (void)in_sizes; (void)n_in; (void)out_size; (void)ws_size;
    const float* x     = (const float*)d_in[0];
    const float* wqkv  = (const float*)d_in[1];
    const float* bqkv  = (const float*)d_in[2];
    const float* gamma = (const float*)d_in[3];
    const float* beta  = (const float*)d_in[4];
    float* out = (float*)d_out;
    unsigned short* ws = (unsigned short*)d_ws;

    unsigned short* wt = ws;                       // 2304*768   bf16
    unsigned short* xb = wt + 2304 * 768;          // 8192*768   bf16
    unsigned short* q  = xb + 8192 * 768;          // 96*1024*64 bf16
    unsigned short* k  = q + 96 * 1024 * 64;       // 96*1024*64 bf16
    unsigned short* vt = k + 96 * 1024 * 64;       // 96*64*1024 bf16
    unsigned short* ab = vt + 96 * 64 * 1024;      // 8192*768   bf16

    kprep<<<7872, 256, 0, stream>>>(x, xb, wqkv, wt);
    kgemm<<<dim3(18, 64), 256, 0, stream>>>(xb, wt, bqkv, q, k, vt);
    kattn<<<dim3(8, 96), 256, 0, stream>>>(q, k, vt, ab);
    kln<<<8192, 192, 0, stream>>>(x, ab, gamma, beta, out);
}

// Round 14
// 205.583 us; speedup vs baseline: 1.0076x; 1.0076x over previous
//
#include <hip/hip_runtime.h>

typedef __attribute__((ext_vector_type(8))) short short8;
typedef __attribute__((ext_vector_type(4))) float f32x4;

#define DEVI __device__ __forceinline__

DEVI unsigned fbits(float f) { return __builtin_bit_cast(unsigned, f); }
DEVI float bf2f(unsigned u) {   // low 16 bits -> f32
    unsigned v = u << 16;
    return __builtin_bit_cast(float, v);
}
DEVI unsigned short f2bf(float f) {
    unsigned u = __builtin_bit_cast(unsigned, f);
    u += 0x7fffu + ((u >> 16) & 1u);   // RNE
    return (unsigned short)(u >> 16);
}
// pack hi16(a)|hi16(b)<<16 (bf16 truncation, 1 instr)
DEVI unsigned pktrunc(float a, float b) {
    return __builtin_amdgcn_perm(fbits(b), fbits(a), 0x07060302u);
}
// async global->LDS, 16 B per lane; LDS dest = uniform base + lane*16
DEVI void async16(const unsigned short* g, unsigned short* l) {
    __builtin_amdgcn_global_load_lds(
        (const __attribute__((address_space(1))) void*)g,
        (__attribute__((address_space(3))) void*)l,
        16, 0, 0);
}
#define BAR()    asm volatile("s_barrier" ::: "memory")
#define BARF()   asm volatile("s_waitcnt lgkmcnt(0)\ns_barrier" ::: "memory")
#define WAITV0() asm volatile("s_waitcnt vmcnt(0)" ::: "memory")

#define SCL 0.18033688011112042f   // log2(e) / sqrt(64), folded into Q

// ---------------------------------------------------------------- prep
// blocks [0,6144): x f32 -> xb bf16 (float4 path)
// blocks [6144,7872): w[768][2304] f32 -> wt[2304][768] bf16 (tiled transpose)
__global__ __launch_bounds__(256) void kprep(const float* __restrict__ x,
                                             unsigned short* __restrict__ xb,
                                             const float* __restrict__ w,
                                             unsigned short* __restrict__ wt) {
    const int bid = blockIdx.x, tid = threadIdx.x;
    if (bid < 6144) {
        const int i = (bid * 256 + tid) * 4;
        const float4 v = *(const float4*)&x[i];
        uint2 pk;
        pk.x = (unsigned)f2bf(v.x) | ((unsigned)f2bf(v.y) << 16);
        pk.y = (unsigned)f2bf(v.z) | ((unsigned)f2bf(v.w) << 16);
        *(uint2*)&xb[i] = pk;
    } else {
        __shared__ float t[32][33];
        const int b2 = bid - 6144;
        const int n0 = (b2 % 72) * 32, k0 = (b2 / 72) * 32;
        const int tx = tid & 31, ty = tid >> 5;   // 32 x 8
#pragma unroll
        for (int i = 0; i < 4; i++)
            t[ty + i * 8][tx] = w[(k0 + ty + i * 8) * 2304 + n0 + tx];
        __syncthreads();
#pragma unroll
        for (int i = 0; i < 4; i++)
            wt[(n0 + ty + i * 8) * 768 + k0 + tx] = f2bf(t[tx][ty + i * 8]);
    }
}

// ---------------------------------------------------------------- QKV GEMM
// A = xb [8192][768] bf16, Bt = wt [2304][768] bf16; C = A*Bt^T + bias.
// Fragment-order LDS, async16 staging, 2-buffer depth-1 pipeline, 34.8 KB
// pool (4 blocks/CU).  XCD-aware tile map: lid&7 = XCD owns m-rows
// [8x,8x+8) x all n  ->  per-XCD L2 working set ~5 MB (A 1.6 + B 3.5).
// Epilogue: q/k direct scatter (q scaled by SCL); v via LDS transpose.
__global__ __launch_bounds__(256) void kgemm(
        const unsigned short* __restrict__ xb,
        const unsigned short* __restrict__ wt,
        const float* __restrict__ bias,
        unsigned short* __restrict__ q,
        unsigned short* __restrict__ k_,
        unsigned short* __restrict__ vt) {
    // staging: As[b] @ b*4096, Bs[b] @ 8192 + b*4096 (b in 0..1)
    // epilogue v-tile [n=128][stride 136] = 17408 elems (34.8 KB)
    __shared__ __align__(16) unsigned short pool[17408];
    const int tid = threadIdx.x;
    const int w = tid >> 6, lane = tid & 63;
    const int wm = w >> 1, wn = w & 1;
    // XCD-aware remap (bijection on 1152 tiles)
    const int lid = blockIdx.y * 18 + blockIdx.x;
    const int xcd = lid & 7, j = lid >> 3;
    const int m0 = (xcd * 8 + j / 18) * 128;
    const int n0 = (j % 18) * 128;
    const int gr = lane & 15, gc = (lane >> 4) * 8;

    f32x4 acc[4][4] = {};

    auto issue = [&](int kk, int b) {
#pragma unroll
        for (int jj = 0; jj < 2; jj++) {
            const int t = w + jj * 4;
            async16(&xb[(m0 + t * 16 + gr) * 768 + kk + gc],
                    &pool[b * 4096 + t * 512 + lane * 8]);
            async16(&wt[(n0 + t * 16 + gr) * 768 + kk + gc],
                    &pool[8192 + b * 4096 + t * 512 + lane * 8]);
        }
    };

    issue(0, 0);

    for (int it = 0; it < 24; it++) {
        const int cur = it & 1;
        WAITV0();          // this wave's DMAs for tile `it` complete
        BAR();             // all waves' tiles resident; prev reads done
        if (it + 1 < 24) issue((it + 1) * 32, cur ^ 1);

        short8 af[4], bf[4];
#pragma unroll
        for (int mi = 0; mi < 4; mi++)
            af[mi] = *(const short8*)&pool[cur * 4096 + (wm * 4 + mi) * 512 + lane * 8];
#pragma unroll
        for (int ni = 0; ni < 4; ni++)
            bf[ni] = *(const short8*)&pool[8192 + cur * 4096 + (wn * 4 + ni) * 512 + lane * 8];
#pragma unroll
        for (int mi = 0; mi < 4; mi++)
#pragma unroll
            for (int ni = 0; ni < 4; ni++)
                acc[mi][ni] = __builtin_amdgcn_mfma_f32_16x16x32_bf16(
                    af[mi], bf[ni], acc[mi][ni], 0, 0, 0);
    }

    const int which = n0 / 768;        // block-uniform: 0=q 1=k 2=v
    const int bb = m0 >> 10, sbase = m0 & 1023;

    if (which == 2) {
        BAR();                         // all staging reads complete
        // C-tile -> LDS transposed [n][136] (bias fused), packed m-quads
#pragma unroll
        for (int mi = 0; mi < 4; mi++) {
            const int mloc = wm * 64 + mi * 16 + (lane >> 4) * 4;
#pragma unroll
            for (int ni = 0; ni < 4; ni++) {
                const int nl = wn * 64 + ni * 16 + gr;
                const float bv = bias[n0 + nl];
                uint2 pk;
                pk.x = pktrunc(acc[mi][ni][0] + bv, acc[mi][ni][1] + bv);
                pk.y = pktrunc(acc[mi][ni][2] + bv, acc[mi][ni][3] + bv);
                *(uint2*)&pool[nl * 136 + mloc] = pk;
            }
        }
        BARF();
        const int h0 = (n0 - 1536) >> 6;
#pragma unroll
        for (int cc = 0; cc < 8; cc++) {
            const int nl = cc * 16 + (tid >> 4);
            const int mc = (tid & 15) * 8;
            short8 vv = *(const short8*)&pool[nl * 136 + mc];
            const int h = h0 + (nl >> 6), d = nl & 63;
            *(short8*)&vt[((bb * 12 + h) * 64 + d) * 1024 + sbase + mc] = vv;
        }
    } else {
        const float qscl = (which == 0) ? SCL : 1.0f;
        const int col0 = n0 + wn * 64;
#pragma unroll
        for (int mi = 0; mi < 4; mi++) {
#pragma unroll
            for (int ni = 0; ni < 4; ni++) {
                const int n_ = col0 + ni * 16 + gr;
                const float bv = bias[n_];
                const int r7 = n_ % 768;
                const int h = r7 >> 6, d = r7 & 63;
                const int bh = bb * 12 + h;
#pragma unroll
                for (int r = 0; r < 4; r++) {
                    const int s = sbase + wm * 64 + mi * 16 + (lane >> 4) * 4 + r;
                    const unsigned short o = f2bf((acc[mi][ni][r] + bv) * qscl);
                    if (which == 0) q[(bh * 1024 + s) * 64 + d] = o;
                    else            k_[(bh * 1024 + s) * 64 + d] = o;
                }
            }
        }
    }
}

// ---------------------------------------------------------------- attention
// S^T = K*Q^T (Q pre-scaled by SCL), softmax over keys WITHOUT online max.
// O^T = V^T*P^T.  Fragment-order async staging, 2-buffer depth-1 pipeline.
// Ps halved (ks-split relayout) -> 40 KB LDS.
__global__ __launch_bounds__(256) void kattn(
        const unsigned short* __restrict__ q,
        const unsigned short* __restrict__ k_,
        const unsigned short* __restrict__ vt,
        unsigned short* __restrict__ attnb) {
    __shared__ __align__(16) unsigned short Ks[2][8 * 512];
    __shared__ __align__(16) unsigned short Vs[2][8 * 512];
    __shared__ __align__(16) unsigned short Ps[4][2 * 512];
    const int tid = threadIdx.x;
    const int w = tid >> 6, lane = tid & 63;
    const int qt = blockIdx.x;          // 8
    const int bh = blockIdx.y;          // 96
    const int bb = bh / 12, h = bh % 12;
    const unsigned short* qb = q + bh * 1024 * 64;
    const unsigned short* kb = k_ + bh * 1024 * 64;
    const unsigned short* vb = vt + bh * 64 * 1024;

    const int frow = lane & 15;         // q-row within 16-tile
    const int grp = lane >> 4;
    const int m0 = qt * 128 + w * 32;

    auto issue = [&](int t0, int b) {
#pragma unroll
        for (int jj = 0; jj < 2; jj++) {
            const int t = w * 2 + jj, ti = t >> 1, ks = t & 1;
            async16(&kb[(t0 + ti * 16 + frow) * 64 + ks * 32 + grp * 8], &Ks[b][t * 512]);
            async16(&vb[(ti * 16 + frow) * 1024 + t0 + ks * 32 + grp * 8], &Vs[b][t * 512]);
        }
    };

    short8 qf[2][2];
#pragma unroll
    for (int mi = 0; mi < 2; mi++)
#pragma unroll
        for (int ks = 0; ks < 2; ks++)
            qf[mi][ks] = *(const short8*)&qb[(m0 + mi * 16 + frow) * 64 + ks * 32 + grp * 8];

    issue(0, 0);

    f32x4 oacc[2][4] = {};
    float rsum[2] = {0.f, 0.f};         // per-lane partial (16 keys/iter)

    for (int tt = 0; tt < 16; tt++) {
        const int cur = tt & 1;
        WAITV0();
        BAR();
        if (tt + 1 < 16) issue((tt + 1) * 64, cur ^ 1);

        // S^T = K * Q^T
        f32x4 sacc[4][2] = {};
#pragma unroll
        for (int ks = 0; ks < 2; ks++) {
            short8 kf[4];
#pragma unroll
            for (int ni = 0; ni < 4; ni++)
                kf[ni] = *(const short8*)&Ks[cur][(ni * 2 + ks) * 512 + lane * 8];
#pragma unroll
            for (int ni = 0; ni < 4; ni++)
#pragma unroll
                for (int mi = 0; mi < 2; mi++)
                    sacc[ni][mi] = __builtin_amdgcn_mfma_f32_16x16x32_bf16(
                        kf[ni], qf[mi][ks], sacc[ni][mi], 0, 0, 0);
        }

        // softmax numerators: p = exp2(s) (scale pre-folded into Q)
#pragma unroll
        for (int mi = 0; mi < 2; mi++) {
            float ps = 0.f;
#pragma unroll
            for (int ni = 0; ni < 4; ni++)
#pragma unroll
                for (int r = 0; r < 4; r++) {
                    const float p = exp2f(sacc[ni][mi][r]);
                    sacc[ni][mi][r] = p;
                    ps += p;
                }
            rsum[mi] += ps;
        }

        // PV per ks-half: relayout that half's P^T, then MFMA
#pragma unroll
        for (int ks = 0; ks < 2; ks++) {
            short8 vf[4], pf[2];
#pragma unroll
            for (int mi = 0; mi < 2; mi++)
#pragma unroll
                for (int nj = 0; nj < 2; nj++) {
                    const int ni = ks * 2 + nj;
                    uint2 pk;
                    pk.x = pktrunc(sacc[ni][mi][0], sacc[ni][mi][1]);
                    pk.y = pktrunc(sacc[ni][mi][2], sacc[ni][mi][3]);
                    const int dlane = frow + (((ni << 1) + (grp >> 1)) & 3) * 16;
                    *(uint2*)&Ps[w][mi * 512 + dlane * 8 + (grp & 1) * 4] = pk;
                }
#pragma unroll
            for (int di = 0; di < 4; di++)
                vf[di] = *(const short8*)&Vs[cur][(di * 2 + ks) * 512 + lane * 8];
#pragma unroll
            for (int mi = 0; mi < 2; mi++)
                pf[mi] = *(const short8*)&Ps[w][mi * 512 + lane * 8];
#pragma unroll
            for (int mi = 0; mi < 2; mi++)
#pragma unroll
                for (int di = 0; di < 4; di++)
                    oacc[mi][di] = __builtin_amdgcn_mfma_f32_16x16x32_bf16(
                        vf[di], pf[mi], oacc[mi][di], 0, 0, 0);
        }
    }

    // epilogue: reduce rsum across the 4 grp lanes, O^T/l -> attnb (bf16)
#pragma unroll
    for (int mi = 0; mi < 2; mi++) {
        float s2 = rsum[mi];
        s2 += __shfl_xor(s2, 16, 64);
        s2 += __shfl_xor(s2, 32, 64);
        const float inv = 1.0f / s2;
        const int s = m0 + mi * 16 + frow;
#pragma unroll
        for (int di = 0; di < 4; di++) {
            f32x4 o = oacc[mi][di] * inv;
            const int d0 = di * 16 + grp * 4;
            uint2 pk;
            pk.x = (unsigned)f2bf(o[0]) | ((unsigned)f2bf(o[1]) << 16);
            pk.y = (unsigned)f2bf(o[2]) | ((unsigned)f2bf(o[3]) << 16);
            *(uint2*)&attnb[(bb * 1024 + s) * 768 + h * 64 + d0] = pk;
        }
    }
}

// ---------------------------------------------------------------- residual + LN
// y = LN(x + attn); x f32 (float4 loads), attn bf16 (uint2 loads), out f32.
__global__ __launch_bounds__(192) void kln(
        const float* __restrict__ x,
        const unsigned short* __restrict__ attnb,
        const float* __restrict__ gamma,
        const float* __restrict__ beta,
        float* __restrict__ out) {
    __shared__ float red[6];
    const int row = blockIdx.x;
    const int tid = threadIdx.x;
    const int e = tid * 4;
    const float4 xv = *(const float4*)&x[row * 768 + e];
    const uint2 av = *(const uint2*)&attnb[row * 768 + e];
    float y0 = xv.x + bf2f(av.x & 0xffffu);
    float y1 = xv.y + bf2f(av.x >> 16);
    float y2 = xv.z + bf2f(av.y & 0xffffu);
    float y3 = xv.w + bf2f(av.y >> 16);
    float sum = y0 + y1 + y2 + y3;
    float sumsq = y0 * y0 + y1 * y1 + y2 * y2 + y3 * y3;
#pragma unroll
    for (int o = 1; o < 64; o <<= 1) {
        sum += __shfl_xor(sum, o, 64);
        sumsq += __shfl_xor(sumsq, o, 64);
    }
    const int w = tid >> 6, lane = tid & 63;
    if (lane == 0) { red[w] = sum; red[3 + w] = sumsq; }
    __syncthreads();
    sum = red[0] + red[1] + red[2];
    sumsq = red[3] + red[4] + red[5];
    const float mean = sum * (1.0f / 768.0f);
    const float var = sumsq * (1.0f / 768.0f) - mean * mean;
    const float rs = rsqrtf(var + 1e-5f);
    const float4 gv = *(const float4*)&gamma[e];
    const float4 bv = *(const float4*)&beta[e];
    float4 ov;
    ov.x = (y0 - mean) * rs * gv.x + bv.x;
    ov.y = (y1 - mean) * rs * gv.y + bv.y;
    ov.z = (y2 - mean) * rs * gv.z + bv.z;
    ov.w = (y3 - mean) * rs * gv.w + bv.w;
    *(float4*)&out[row * 768 + e] = ov;
}

// ---------------------------------------------------------------- launch
extern "C" void kernel_launch(void* const* d_in, const int* in_sizes, int n_in,
                              void* d_out, int out_size, void* d_ws, size_t ws_size,
                              hipStream_t stream) {
    (void)in_sizes; (void)n_in; (void)out_size; (void)ws_size;
    const float* x     = (const float*)d_in[0];
    const float* wqkv  = (const float*)d_in[1];
    const float* bqkv  = (const float*)d_in[2];
    const float* gamma = (const float*)d_in[3];
    const float* beta  = (const float*)d_in[4];
    float* out = (float*)d_out;
    unsigned short* ws = (unsigned short*)d_ws;

    unsigned short* wt = ws;                       // 2304*768   bf16
    unsigned short* xb = wt + 2304 * 768;          // 8192*768   bf16
    unsigned short* q  = xb + 8192 * 768;          // 96*1024*64 bf16
    unsigned short* k  = q + 96 * 1024 * 64;       // 96*1024*64 bf16
    unsigned short* vt = k + 96 * 1024 * 64;       // 96*64*1024 bf16
    unsigned short* ab = vt + 96 * 64 * 1024;      // 8192*768   bf16

    kprep<<<7872, 256, 0, stream>>>(x, xb, wqkv, wt);
    kgemm<<<dim3(18, 64), 256, 0, stream>>>(xb, wt, bqkv, q, k, vt);
    kattn<<<dim3(8, 96), 256, 0, stream>>>(q, k, vt, ab);
    kln<<<8192, 192, 0, stream>>>(x, ab, gamma, beta, out);
}

// Round 15
// 203.921 us; speedup vs baseline: 1.0158x; 1.0082x over previous
//
#include <hip/hip_runtime.h>

typedef __attribute__((ext_vector_type(8))) short short8;
typedef __attribute__((ext_vector_type(4))) float f32x4;

#define DEVI __device__ __forceinline__

DEVI unsigned fbits(float f) { return __builtin_bit_cast(unsigned, f); }
DEVI float bf2f(unsigned u) {   // low 16 bits -> f32
    unsigned v = u << 16;
    return __builtin_bit_cast(float, v);
}
DEVI unsigned short f2bf(float f) {
    unsigned u = __builtin_bit_cast(unsigned, f);
    u += 0x7fffu + ((u >> 16) & 1u);   // RNE
    return (unsigned short)(u >> 16);
}
// pack hi16(a)|hi16(b)<<16 (bf16 truncation, 1 instr)
DEVI unsigned pktrunc(float a, float b) {
    return __builtin_amdgcn_perm(fbits(b), fbits(a), 0x07060302u);
}
// async global->LDS, 16 B per lane; LDS dest = uniform base + lane*16
DEVI void async16(const unsigned short* g, unsigned short* l) {
    __builtin_amdgcn_global_load_lds(
        (const __attribute__((address_space(1))) void*)g,
        (__attribute__((address_space(3))) void*)l,
        16, 0, 0);
}
#define BAR()    asm volatile("s_barrier" ::: "memory")
#define BARF()   asm volatile("s_waitcnt lgkmcnt(0)\ns_barrier" ::: "memory")
#define WAITV0() asm volatile("s_waitcnt vmcnt(0)" ::: "memory")

#define SCL 0.18033688011112042f   // log2(e) / sqrt(64), folded into Q

// ---------------------------------------------------------------- prep
// blocks [0,6144): x f32 -> xb bf16 (float4 path)
// blocks [6144,7872): w[768][2304] f32 -> wt[2304][768] bf16 (tiled transpose)
__global__ __launch_bounds__(256) void kprep(const float* __restrict__ x,
                                             unsigned short* __restrict__ xb,
                                             const float* __restrict__ w,
                                             unsigned short* __restrict__ wt) {
    const int bid = blockIdx.x, tid = threadIdx.x;
    if (bid < 6144) {
        const int i = (bid * 256 + tid) * 4;
        const float4 v = *(const float4*)&x[i];
        uint2 pk;
        pk.x = (unsigned)f2bf(v.x) | ((unsigned)f2bf(v.y) << 16);
        pk.y = (unsigned)f2bf(v.z) | ((unsigned)f2bf(v.w) << 16);
        *(uint2*)&xb[i] = pk;
    } else {
        __shared__ float t[32][33];
        const int b2 = bid - 6144;
        const int n0 = (b2 % 72) * 32, k0 = (b2 / 72) * 32;
        const int tx = tid & 31, ty = tid >> 5;   // 32 x 8
#pragma unroll
        for (int i = 0; i < 4; i++)
            t[ty + i * 8][tx] = w[(k0 + ty + i * 8) * 2304 + n0 + tx];
        __syncthreads();
#pragma unroll
        for (int i = 0; i < 4; i++)
            wt[(n0 + ty + i * 8) * 768 + k0 + tx] = f2bf(t[tx][ty + i * 8]);
    }
}

// ---------------------------------------------------------------- QKV GEMM
// A = xb [8192][768] bf16, Bt = wt [2304][768] bf16; C = A*Bt^T + bias.
// Fragment-order LDS, async16 staging, 2-buffer depth-1 pipeline, 34.8 KB
// pool (4 blocks/CU).  XCD-aware tile map (XCD = lid&7, verified R14:
// FETCH 64->35 MB): XCD x owns m-rows [8x,8x+8) x all n.
// Epilogue: q/k direct scatter (q scaled by SCL); v via LDS transpose.
__global__ __launch_bounds__(256) void kgemm(
        const unsigned short* __restrict__ xb,
        const unsigned short* __restrict__ wt,
        const float* __restrict__ bias,
        unsigned short* __restrict__ q,
        unsigned short* __restrict__ k_,
        unsigned short* __restrict__ vt) {
    // staging: As[b] @ b*4096, Bs[b] @ 8192 + b*4096 (b in 0..1)
    // epilogue v-tile [n=128][stride 136] = 17408 elems (34.8 KB)
    __shared__ __align__(16) unsigned short pool[17408];
    const int tid = threadIdx.x;
    const int w = tid >> 6, lane = tid & 63;
    const int wm = w >> 1, wn = w & 1;
    // XCD-aware remap (bijection on 1152 tiles)
    const int lid = blockIdx.y * 18 + blockIdx.x;
    const int xcd = lid & 7, j = lid >> 3;
    const int m0 = (xcd * 8 + j / 18) * 128;
    const int n0 = (j % 18) * 128;
    const int gr = lane & 15, gc = (lane >> 4) * 8;

    f32x4 acc[4][4] = {};

    auto issue = [&](int kk, int b) {
#pragma unroll
        for (int jj = 0; jj < 2; jj++) {
            const int t = w + jj * 4;
            async16(&xb[(m0 + t * 16 + gr) * 768 + kk + gc],
                    &pool[b * 4096 + t * 512 + lane * 8]);
            async16(&wt[(n0 + t * 16 + gr) * 768 + kk + gc],
                    &pool[8192 + b * 4096 + t * 512 + lane * 8]);
        }
    };

    issue(0, 0);

    for (int it = 0; it < 24; it++) {
        const int cur = it & 1;
        WAITV0();          // this wave's DMAs for tile `it` complete
        BAR();             // all waves' tiles resident; prev reads done
        if (it + 1 < 24) issue((it + 1) * 32, cur ^ 1);

        short8 af[4], bf[4];
#pragma unroll
        for (int mi = 0; mi < 4; mi++)
            af[mi] = *(const short8*)&pool[cur * 4096 + (wm * 4 + mi) * 512 + lane * 8];
#pragma unroll
        for (int ni = 0; ni < 4; ni++)
            bf[ni] = *(const short8*)&pool[8192 + cur * 4096 + (wn * 4 + ni) * 512 + lane * 8];
#pragma unroll
        for (int mi = 0; mi < 4; mi++)
#pragma unroll
            for (int ni = 0; ni < 4; ni++)
                acc[mi][ni] = __builtin_amdgcn_mfma_f32_16x16x32_bf16(
                    af[mi], bf[ni], acc[mi][ni], 0, 0, 0);
    }

    const int which = n0 / 768;        // block-uniform: 0=q 1=k 2=v
    const int bb = m0 >> 10, sbase = m0 & 1023;

    if (which == 2) {
        BAR();                         // all staging reads complete
        // C-tile -> LDS transposed [n][136] (bias fused), packed m-quads
#pragma unroll
        for (int mi = 0; mi < 4; mi++) {
            const int mloc = wm * 64 + mi * 16 + (lane >> 4) * 4;
#pragma unroll
            for (int ni = 0; ni < 4; ni++) {
                const int nl = wn * 64 + ni * 16 + gr;
                const float bv = bias[n0 + nl];
                uint2 pk;
                pk.x = pktrunc(acc[mi][ni][0] + bv, acc[mi][ni][1] + bv);
                pk.y = pktrunc(acc[mi][ni][2] + bv, acc[mi][ni][3] + bv);
                *(uint2*)&pool[nl * 136 + mloc] = pk;
            }
        }
        BARF();
        const int h0 = (n0 - 1536) >> 6;
#pragma unroll
        for (int cc = 0; cc < 8; cc++) {
            const int nl = cc * 16 + (tid >> 4);
            const int mc = (tid & 15) * 8;
            short8 vv = *(const short8*)&pool[nl * 136 + mc];
            const int h = h0 + (nl >> 6), d = nl & 63;
            *(short8*)&vt[((bb * 12 + h) * 64 + d) * 1024 + sbase + mc] = vv;
        }
    } else {
        const float qscl = (which == 0) ? SCL : 1.0f;
        const int col0 = n0 + wn * 64;
#pragma unroll
        for (int mi = 0; mi < 4; mi++) {
#pragma unroll
            for (int ni = 0; ni < 4; ni++) {
                const int n_ = col0 + ni * 16 + gr;
                const float bv = bias[n_];
                const int r7 = n_ % 768;
                const int h = r7 >> 6, d = r7 & 63;
                const int bh = bb * 12 + h;
#pragma unroll
                for (int r = 0; r < 4; r++) {
                    const int s = sbase + wm * 64 + mi * 16 + (lane >> 4) * 4 + r;
                    const unsigned short o = f2bf((acc[mi][ni][r] + bv) * qscl);
                    if (which == 0) q[(bh * 1024 + s) * 64 + d] = o;
                    else            k_[(bh * 1024 + s) * 64 + d] = o;
                }
            }
        }
    }
}

// ---------------------------------------------------------------- attention
// S^T = K*Q^T (Q pre-scaled by SCL), softmax over keys WITHOUT online max.
// O^T = V^T*P^T.  Fragment-order async staging, 2-buffer depth-1 pipeline,
// Ps ks-split (40 KB LDS).  Grid (96,8): x=bh, y=qt -> lid&7 = bh&7, so
// all 8 q-tiles of a head share one XCD; 12 heads/XCD = 3 MB K/V in L2.
__global__ __launch_bounds__(256) void kattn(
        const unsigned short* __restrict__ q,
        const unsigned short* __restrict__ k_,
        const unsigned short* __restrict__ vt,
        unsigned short* __restrict__ attnb) {
    __shared__ __align__(16) unsigned short Ks[2][8 * 512];
    __shared__ __align__(16) unsigned short Vs[2][8 * 512];
    __shared__ __align__(16) unsigned short Ps[4][2 * 512];
    const int tid = threadIdx.x;
    const int w = tid >> 6, lane = tid & 63;
    const int bh = blockIdx.x;          // 96
    const int qt = blockIdx.y;          // 8
    const int bb = bh / 12, h = bh % 12;
    const unsigned short* qb = q + bh * 1024 * 64;
    const unsigned short* kb = k_ + bh * 1024 * 64;
    const unsigned short* vb = vt + bh * 64 * 1024;

    const int frow = lane & 15;         // q-row within 16-tile
    const int grp = lane >> 4;
    const int m0 = qt * 128 + w * 32;

    auto issue = [&](int t0, int b) {
#pragma unroll
        for (int jj = 0; jj < 2; jj++) {
            const int t = w * 2 + jj, ti = t >> 1, ks = t & 1;
            async16(&kb[(t0 + ti * 16 + frow) * 64 + ks * 32 + grp * 8], &Ks[b][t * 512]);
            async16(&vb[(ti * 16 + frow) * 1024 + t0 + ks * 32 + grp * 8], &Vs[b][t * 512]);
        }
    };

    short8 qf[2][2];
#pragma unroll
    for (int mi = 0; mi < 2; mi++)
#pragma unroll
        for (int ks = 0; ks < 2; ks++)
            qf[mi][ks] = *(const short8*)&qb[(m0 + mi * 16 + frow) * 64 + ks * 32 + grp * 8];

    issue(0, 0);

    f32x4 oacc[2][4] = {};
    float rsum[2] = {0.f, 0.f};         // per-lane partial (16 keys/iter)

    for (int tt = 0; tt < 16; tt++) {
        const int cur = tt & 1;
        WAITV0();
        BAR();
        if (tt + 1 < 16) issue((tt + 1) * 64, cur ^ 1);

        // S^T = K * Q^T
        f32x4 sacc[4][2] = {};
#pragma unroll
        for (int ks = 0; ks < 2; ks++) {
            short8 kf[4];
#pragma unroll
            for (int ni = 0; ni < 4; ni++)
                kf[ni] = *(const short8*)&Ks[cur][(ni * 2 + ks) * 512 + lane * 8];
#pragma unroll
            for (int ni = 0; ni < 4; ni++)
#pragma unroll
                for (int mi = 0; mi < 2; mi++)
                    sacc[ni][mi] = __builtin_amdgcn_mfma_f32_16x16x32_bf16(
                        kf[ni], qf[mi][ks], sacc[ni][mi], 0, 0, 0);
        }

        // softmax numerators: p = exp2(s) (scale pre-folded into Q)
#pragma unroll
        for (int mi = 0; mi < 2; mi++) {
            float ps = 0.f;
#pragma unroll
            for (int ni = 0; ni < 4; ni++)
#pragma unroll
                for (int r = 0; r < 4; r++) {
                    const float p = exp2f(sacc[ni][mi][r]);
                    sacc[ni][mi][r] = p;
                    ps += p;
                }
            rsum[mi] += ps;
        }

        // PV per ks-half: relayout that half's P^T, then MFMA
#pragma unroll
        for (int ks = 0; ks < 2; ks++) {
            short8 vf[4], pf[2];
#pragma unroll
            for (int mi = 0; mi < 2; mi++)
#pragma unroll
                for (int nj = 0; nj < 2; nj++) {
                    const int ni = ks * 2 + nj;
                    uint2 pk;
                    pk.x = pktrunc(sacc[ni][mi][0], sacc[ni][mi][1]);
                    pk.y = pktrunc(sacc[ni][mi][2], sacc[ni][mi][3]);
                    const int dlane = frow + (((ni << 1) + (grp >> 1)) & 3) * 16;
                    *(uint2*)&Ps[w][mi * 512 + dlane * 8 + (grp & 1) * 4] = pk;
                }
#pragma unroll
            for (int di = 0; di < 4; di++)
                vf[di] = *(const short8*)&Vs[cur][(di * 2 + ks) * 512 + lane * 8];
#pragma unroll
            for (int mi = 0; mi < 2; mi++)
                pf[mi] = *(const short8*)&Ps[w][mi * 512 + lane * 8];
#pragma unroll
            for (int mi = 0; mi < 2; mi++)
#pragma unroll
                for (int di = 0; di < 4; di++)
                    oacc[mi][di] = __builtin_amdgcn_mfma_f32_16x16x32_bf16(
                        vf[di], pf[mi], oacc[mi][di], 0, 0, 0);
        }
    }

    // epilogue: reduce rsum across the 4 grp lanes, O^T/l -> attnb (bf16)
#pragma unroll
    for (int mi = 0; mi < 2; mi++) {
        float s2 = rsum[mi];
        s2 += __shfl_xor(s2, 16, 64);
        s2 += __shfl_xor(s2, 32, 64);
        const float inv = 1.0f / s2;
        const int s = m0 + mi * 16 + frow;
#pragma unroll
        for (int di = 0; di < 4; di++) {
            f32x4 o = oacc[mi][di] * inv;
            const int d0 = di * 16 + grp * 4;
            uint2 pk;
            pk.x = (unsigned)f2bf(o[0]) | ((unsigned)f2bf(o[1]) << 16);
            pk.y = (unsigned)f2bf(o[2]) | ((unsigned)f2bf(o[3]) << 16);
            *(uint2*)&attnb[(bb * 1024 + s) * 768 + h * 64 + d0] = pk;
        }
    }
}

// ---------------------------------------------------------------- residual + LN
// y = LN(x + attn); x f32 (float4 loads), attn bf16 (uint2 loads), out f32.
__global__ __launch_bounds__(192) void kln(
        const float* __restrict__ x,
        const unsigned short* __restrict__ attnb,
        const float* __restrict__ gamma,
        const float* __restrict__ beta,
        float* __restrict__ out) {
    __shared__ float red[6];
    const int row = blockIdx.x;
    const int tid = threadIdx.x;
    const int e = tid * 4;
    const float4 xv = *(const float4*)&x[row * 768 + e];
    const uint2 av = *(const uint2*)&attnb[row * 768 + e];
    float y0 = xv.x + bf2f(av.x & 0xffffu);
    float y1 = xv.y + bf2f(av.x >> 16);
    float y2 = xv.z + bf2f(av.y & 0xffffu);
    float y3 = xv.w + bf2f(av.y >> 16);
    float sum = y0 + y1 + y2 + y3;
    float sumsq = y0 * y0 + y1 * y1 + y2 * y2 + y3 * y3;
#pragma unroll
    for (int o = 1; o < 64; o <<= 1) {
        sum += __shfl_xor(sum, o, 64);
        sumsq += __shfl_xor(sumsq, o, 64);
    }
    const int w = tid >> 6, lane = tid & 63;
    if (lane == 0) { red[w] = sum; red[3 + w] = sumsq; }
    __syncthreads();
    sum = red[0] + red[1] + red[2];
    sumsq = red[3] + red[4] + red[5];
    const float mean = sum * (1.0f / 768.0f);
    const float var = sumsq * (1.0f / 768.0f) - mean * mean;
    const float rs = rsqrtf(var + 1e-5f);
    const float4 gv = *(const float4*)&gamma[e];
    const float4 bv = *(const float4*)&beta[e];
    float4 ov;
    ov.x = (y0 - mean) * rs * gv.x + bv.x;
    ov.y = (y1 - mean) * rs * gv.y + bv.y;
    ov.z = (y2 - mean) * rs * gv.z + bv.z;
    ov.w = (y3 - mean) * rs * gv.w + bv.w;
    *(float4*)&out[row * 768 + e] = ov;
}

// ---------------------------------------------------------------- launch
extern "C" void kernel_launch(void* const* d_in, const int* in_sizes, int n_in,
                              void* d_out, int out_size, void* d_ws, size_t ws_size,
                              hipStream_t stream) {
    (void)in_sizes; (void)n_in; (void)out_size; (void)ws_size;
    const float* x     = (const float*)d_in[0];
    const float* wqkv  = (const float*)d_in[1];
    const float* bqkv  = (const float*)d_in[2];
    const float* gamma = (const float*)d_in[3];
    const float* beta  = (const float*)d_in[4];
    float* out = (float*)d_out;
    unsigned short* ws = (unsigned short*)d_ws;

    unsigned short* wt = ws;                       // 2304*768   bf16
    unsigned short* xb = wt + 2304 * 768;          // 8192*768   bf16
    unsigned short* q  = xb + 8192 * 768;          // 96*1024*64 bf16
    unsigned short* k  = q + 96 * 1024 * 64;       // 96*1024*64 bf16
    unsigned short* vt = k + 96 * 1024 * 64;       // 96*64*1024 bf16
    unsigned short* ab = vt + 96 * 64 * 1024;      // 8192*768   bf16

    kprep<<<7872, 256, 0, stream>>>(x, xb, wqkv, wt);
    kgemm<<<dim3(18, 64), 256, 0, stream>>>(xb, wt, bqkv, q, k, vt);
    kattn<<<dim3(96, 8), 256, 0, stream>>>(q, k, vt, ab);
    kln<<<8192, 192, 0, stream>>>(x, ab, gamma, beta, out);
}